// Round 2
// baseline (1663.643 us; speedup 1.0000x reference)
//
#include <hip/hip_runtime.h>
#include <stdint.h>

typedef unsigned short u16;
typedef unsigned int u32;
typedef __attribute__((ext_vector_type(8))) short short8;
typedef __attribute__((ext_vector_type(4))) float f32x4;

#define BB 4
#define TT 1024
#define CC 2048

// ---------- helpers ----------
__device__ __forceinline__ u16 f2bf(float f){
  union { float f; u32 u; } v; v.f = f;
  return (u16)((v.u + 0x7FFFu + ((v.u >> 16) & 1u)) >> 16);
}
__device__ __forceinline__ float bf2f(u16 h){
  union { u32 u; float f; } v; v.u = ((u32)h) << 16; return v.f;
}

__device__ __forceinline__ void gload16(const void* g, void* s){
  __builtin_amdgcn_global_load_lds((const __attribute__((address_space(1))) u32*)g,
                                   (__attribute__((address_space(3))) u32*)s, 16, 0, 0);
}

__device__ __forceinline__ float wave_sum64(float x){
  #pragma unroll
  for (int m = 1; m < 64; m <<= 1) x += __shfl_xor(x, m, 64);
  return x;
}

// ---------- cast f32 -> bf16 ----------
__global__ __launch_bounds__(256) void k_cast(const float* __restrict__ in, u16* __restrict__ out, int n){
  int i = (blockIdx.x*256 + threadIdx.x)*4;
  if (i >= n) return;
  float4 v = *(const float4*)&in[i];
  *(ushort4*)&out[i] = make_ushort4(f2bf(v.x), f2bf(v.y), f2bf(v.z), f2bf(v.w));
}

// ---------- transpose + pad: in (R,S) f32 -> out (Spad, Rpad) bf16, out[s][r]=in[r][s] ----------
__global__ __launch_bounds__(256) void k_tpad(const float* __restrict__ in, u16* __restrict__ out,
                                              int R, int S, int Rpad, int Spad){
  int idx = blockIdx.x*256 + threadIdx.x;
  if (idx >= Rpad*Spad) return;
  int s = idx / Rpad, r = idx - s*Rpad;
  float v = (s < S && r < R) ? in[(size_t)r*S + s] : 0.f;
  out[idx] = f2bf(v);
}

// ---------- GEMM: C[M,N] = A[M,K](bf16) * Bt[N,K]^T(bf16) ----------
// AMODE 0: A from bf16 buffer via global_load_lds.
// AMODE 1: A = x + (xprev - x)*mix computed on the fly (f32 sources), mix chosen by blockIdx.x.
// EPI 0: f32 out. EPI 1: bf16 out. EPI 2: bf16 out with stage-1 activation by blockIdx.x.
template<int AMODE, int EPI>
__global__ __launch_bounds__(256) void k_gemm(
  const u16* __restrict__ Abf,
  const float* __restrict__ xg, const float* __restrict__ shiftg,
  const float* __restrict__ mx0, const float* __restrict__ mx1,
  const float* __restrict__ mx2, const float* __restrict__ mx3,
  const u16* __restrict__ Bt, float* __restrict__ Cf, u16* __restrict__ Cb,
  int K, int lda, int ldb, int ldc)
{
  __shared__ alignas(16) u16 sA[128*32];
  __shared__ alignas(16) u16 sB[128*32];
  const int tid = threadIdx.x;
  const int wv = tid >> 6, ln = tid & 63;
  const int bx = blockIdx.x;
  const int row0 = blockIdx.y * 128, col0 = bx * 128;
  const int wr = wv >> 1, wc = wv & 1;
  const float* mixv = nullptr;
  if (AMODE == 1) mixv = (bx==0) ? mx0 : (bx==1) ? mx1 : (bx==2) ? mx2 : mx3;

  f32x4 acc[4][4] = {};
  const int ob0 = wv*2048;            // wave-uniform LDS byte base
  const int o0  = ob0 + ln*16;        // per-lane linear byte offset
  const int rA0 = o0 >> 6;            // tile row (64B per row: 32 bf16)
  const int ke0 = (o0 & 63) >> 1;     // element offset along K
  const int ar  = tid >> 2;           // 0..63 (reg-stage row)
  const int akc = (tid & 3) * 8;      // 0,8,16,24 (reg-stage k offset)

  for (int k0 = 0; k0 < K; k0 += 32){
    __syncthreads();
    if (AMODE == 0){
      gload16(&Abf[(size_t)(row0 + rA0     )*lda + k0 + ke0], (void*)((char*)sA + ob0));
      gload16(&Abf[(size_t)(row0 + rA0 + 16)*lda + k0 + ke0], (void*)((char*)sA + ob0 + 1024));
    }
    gload16(&Bt[(size_t)(col0 + rA0     )*ldb + k0 + ke0], (void*)((char*)sB + ob0));
    gload16(&Bt[(size_t)(col0 + rA0 + 16)*ldb + k0 + ke0], (void*)((char*)sB + ob0 + 1024));
    if (AMODE == 1){
      float4 m0 = *(const float4*)&mixv[k0 + akc];
      float4 m1 = *(const float4*)&mixv[k0 + akc + 4];
      #pragma unroll
      for (int it = 0; it < 2; ++it){
        int r = ar + it*64;
        int gr = row0 + r;
        size_t xo = (size_t)gr*CC + k0 + akc;
        float4 c0 = *(const float4*)&xg[xo];
        float4 c1 = *(const float4*)&xg[xo + 4];
        const float* pp = ((gr & (TT-1)) == 0) ? &shiftg[(size_t)(gr >> 10)*CC + k0 + akc]
                                               : &xg[xo - CC];
        float4 p0 = *(const float4*)&pp[0];
        float4 p1 = *(const float4*)&pp[4];
        short8 vv;
        vv[0] = (short)f2bf(c0.x + (p0.x - c0.x)*m0.x);
        vv[1] = (short)f2bf(c0.y + (p0.y - c0.y)*m0.y);
        vv[2] = (short)f2bf(c0.z + (p0.z - c0.z)*m0.z);
        vv[3] = (short)f2bf(c0.w + (p0.w - c0.w)*m0.w);
        vv[4] = (short)f2bf(c1.x + (p1.x - c1.x)*m1.x);
        vv[5] = (short)f2bf(c1.y + (p1.y - c1.y)*m1.y);
        vv[6] = (short)f2bf(c1.z + (p1.z - c1.z)*m1.z);
        vv[7] = (short)f2bf(c1.w + (p1.w - c1.w)*m1.w);
        *(short8*)&sA[r*32 + akc] = vv;
      }
    }
    __syncthreads();
    short8 aF[4], bF[4];
    #pragma unroll
    for (int m=0;m<4;m++) aF[m] = *(const short8*)&sA[(wr*64 + m*16 + (ln&15))*32 + (ln>>4)*8];
    #pragma unroll
    for (int n=0;n<4;n++) bF[n] = *(const short8*)&sB[(wc*64 + n*16 + (ln&15))*32 + (ln>>4)*8];
    #pragma unroll
    for (int m=0;m<4;m++)
      #pragma unroll
      for (int n=0;n<4;n++)
        acc[m][n] = __builtin_amdgcn_mfma_f32_16x16x32_bf16(aF[m], bF[n], acc[m][n], 0,0,0);
  }

  const int cr = (ln >> 4) * 4, ccol = ln & 15;
  #pragma unroll
  for (int m=0;m<4;m++){
    #pragma unroll
    for (int n=0;n<4;n++){
      int gc = col0 + wc*64 + n*16 + ccol;
      #pragma unroll
      for (int j=0;j<4;j++){
        int gr = row0 + wr*64 + m*16 + cr + j;
        float v = acc[m][n][j];
        if (EPI == 0){
          Cf[(size_t)gr*ldc + gc] = v;
        } else if (EPI == 1){
          Cb[(size_t)gr*ldc + gc] = f2bf(v);
        } else {
          if (bx == 0) v = tanhf(v);
          else if (bx >= 3) v = 1.f/(1.f + expf(-v));
          Cb[(size_t)gr*ldc + gc] = f2bf(v);
        }
      }
    }
  }
}

// ---------- post1: elementwise + kk-normalize; bf16 in/out, decay f32 ----------
__global__ __launch_bounds__(256) void k_post1(
  u16* __restrict__ kb, u16* __restrict__ vb, const u16* __restrict__ winb,
  u16* __restrict__ ainb, u16* __restrict__ vinb,
  const float* __restrict__ vfirst,
  const float* __restrict__ w0, const float* __restrict__ a0, const float* __restrict__ v0,
  const float* __restrict__ kkv, const float* __restrict__ kav,
  float* __restrict__ dec)
{
  int grp = blockIdx.x*4 + (threadIdx.x >> 6);
  int n = threadIdx.x & 63;
  int i = grp >> 5, h = grp & 31;
  int c = h*64 + n;
  size_t idx = (size_t)i*CC + c;
  float k  = bf2f(kb[idx]),  v = bf2f(vb[idx]);
  float wi = bf2f(winb[idx]), ai = bf2f(ainb[idx]), vi = bf2f(vinb[idx]);
  float vf = vfirst[idx];
  float a  = 1.f/(1.f + expf(-(a0[c] + ai)));
  float z  = -(w0[c] + wi);
  float sp = (z > 15.f) ? z : log1pf(expf(z));
  float decay = expf(-expf(-sp - 0.5f));
  float vg = 1.f/(1.f + expf(-(v0[c] + vi)));
  float vfin = v + (vf - v)*vg;
  float kkr = k * kkv[c];
  float ss = wave_sum64(kkr*kkr);
  float kkn = kkr / fmaxf(sqrtf(ss), 1e-12f);
  float kfin = k * (1.f + (a - 1.f)*kav[c]);
  kb[idx] = f2bf(kfin);
  vb[idx] = f2bf(vfin);
  dec[idx] = decay;
  vinb[idx] = f2bf(kkn);
  ainb[idx] = f2bf(kkn * a);
}

// ---------- WKV scan: 256 blocks = 128 (b,h) x 2 row-halves; 128 threads ----------
__global__ __launch_bounds__(128) void k_scan(
  const u16* __restrict__ rb, const float* __restrict__ wb,
  const u16* __restrict__ kb, const u16* __restrict__ vb,
  const u16* __restrict__ kkb, const u16* __restrict__ bbp,
  const float* __restrict__ wkv_in, u16* __restrict__ yb, float* __restrict__ wkv_out)
{
  const int blk = blockIdx.x;
  const int bh = blk >> 1, rh = blk & 1;     // bh = b*32+h
  const int b = bh >> 5, h = bh & 31;
  const int tid = threadIdx.x;
  const int v_ = tid & 31, wq = tid >> 5;    // row within half, col-quarter
  const int n0 = wq * 16;
  const int wv2 = tid >> 6, nl = tid & 63;   // staging roles

  __shared__ float  skk[64];
  __shared__ float  sv[64];
  __shared__ float4 sq[64];                  // (w, b, k, r)
  __shared__ float  part[4][32];
  __shared__ float  ypart[4][32];

  float st[16];
  {
    const float* w0p = wkv_in + ((size_t)bh*64 + rh*32 + v_)*64 + n0;
    #pragma unroll
    for (int i=0;i<16;i++) st[i] = w0p[i];
  }
  size_t base = ((size_t)b*TT)*CC + h*64;    // advances by CC per step
  float pf0, pf1, pf2;

  if (wv2 == 0){ pf0 = bf2f(kkb[base+nl]); pf1 = bf2f(bbp[base+nl]); pf2 = bf2f(rb[base+nl]); }
  else         { pf0 = wb[base+nl];        pf1 = bf2f(kb[base+nl]);  pf2 = bf2f(vb[base+nl]); }

  for (int t=0; t<TT; ++t){
    if (wv2 == 0){ skk[nl] = pf0; sq[nl].y = pf1; sq[nl].w = pf2; }
    else         { sq[nl].x = pf0; sq[nl].z = pf1; sv[nl] = pf2; }
    __syncthreads();
    if (t < TT-1){
      size_t nb = base + CC;
      if (wv2 == 0){ pf0 = bf2f(kkb[nb+nl]); pf1 = bf2f(bbp[nb+nl]); pf2 = bf2f(rb[nb+nl]); }
      else         { pf0 = wb[nb+nl];        pf1 = bf2f(kb[nb+nl]);  pf2 = bf2f(vb[nb+nl]); }
    }
    float p = 0.f;
    #pragma unroll
    for (int i=0;i<16;i++) p += st[i]*skk[n0+i];
    part[wq][v_] = p;
    float vv = sv[rh*32 + v_];
    __syncthreads();
    float sa = -(part[0][v_] + part[1][v_] + part[2][v_] + part[3][v_]);
    float y = 0.f;
    #pragma unroll
    for (int i=0;i<16;i++){
      float4 qq = sq[n0+i];
      float s2 = st[i]*qq.x + sa*qq.y + vv*qq.z;
      st[i] = s2;
      y += s2*qq.w;
    }
    ypart[wq][v_] = y;
    __syncthreads();
    if (wq == 0){
      float yy = ypart[0][v_] + ypart[1][v_] + ypart[2][v_] + ypart[3][v_];
      yb[base + rh*32 + v_] = f2bf(yy);
    }
    base += CC;
  }
  float* wo = wkv_out + ((size_t)bh*64 + rh*32 + v_)*64 + n0;
  #pragma unroll
  for (int i=0;i<16;i++) wo[i] = st[i];
}

// ---------- post2: groupnorm + bonus + gate -> bf16 A for final GEMM ----------
__global__ __launch_bounds__(256) void k_post2(
  const u16* __restrict__ ybuf, const u16* __restrict__ rbuf,
  const u16* __restrict__ kfb, const u16* __restrict__ vfb,
  const u16* __restrict__ gbuf, const float* __restrict__ rk,
  const float* __restrict__ lnw, const float* __restrict__ lnb, u16* __restrict__ ao)
{
  int grp = blockIdx.x*4 + (threadIdx.x >> 6);
  int n = threadIdx.x & 63;
  int i = grp >> 5, h = grp & 31;
  int c = h*64 + n;
  size_t idx = (size_t)i*CC + c;
  float y = bf2f(ybuf[idx]);
  float s1 = wave_sum64(y);
  float s2 = wave_sum64(y*y);
  float mu = s1 * (1.f/64.f);
  float var = s2 * (1.f/64.f) - mu*mu;
  float yn = (y - mu) * rsqrtf(var + 6.4e-4f) * lnw[c] + lnb[c];
  float rv = bf2f(rbuf[idx]), kv = bf2f(kfb[idx]);
  float s3 = wave_sum64(rv * kv * rk[c]);
  float bonus = s3 * bf2f(vfb[idx]);
  ao[idx] = f2bf((yn + bonus) * bf2f(gbuf[idx]));
}

// ---------- shift_state_out = x[:, -1] ----------
__global__ __launch_bounds__(256) void k_shift(const float* __restrict__ x, float* __restrict__ so){
  int i = blockIdx.x*256 + threadIdx.x;   // 2048 threads x 4 floats
  int b = i >> 9, c4 = (i & 511)*4;
  *(float4*)&so[(size_t)b*CC + c4] = *(const float4*)&x[((size_t)(b*TT + TT-1))*CC + c4];
}

// ---------- launch ----------
extern "C" void kernel_launch(void* const* d_in, const int* in_sizes, int n_in,
                              void* d_out, int out_size, void* d_ws, size_t ws_size,
                              hipStream_t stream)
{
  const float* x        = (const float*)d_in[0];
  const float* shift_in = (const float*)d_in[1];
  const float* wkv_in   = (const float*)d_in[2];
  const float* v_first  = (const float*)d_in[3];
  const float* x_r = (const float*)d_in[4];
  const float* x_w = (const float*)d_in[5];
  const float* x_k = (const float*)d_in[6];
  const float* x_v = (const float*)d_in[7];
  const float* x_a = (const float*)d_in[8];
  const float* x_g = (const float*)d_in[9];
  const float* w0 = (const float*)d_in[10];
  const float* w1 = (const float*)d_in[11];
  const float* w2 = (const float*)d_in[12];
  const float* a0 = (const float*)d_in[13];
  const float* a1 = (const float*)d_in[14];
  const float* a2 = (const float*)d_in[15];
  const float* v0 = (const float*)d_in[16];
  const float* v1 = (const float*)d_in[17];
  const float* v2 = (const float*)d_in[18];
  const float* g1 = (const float*)d_in[19];
  const float* g2 = (const float*)d_in[20];
  const float* k_k = (const float*)d_in[21];
  const float* k_a = (const float*)d_in[22];
  const float* r_k = (const float*)d_in[23];
  const float* Wr = (const float*)d_in[24];
  const float* Wk = (const float*)d_in[25];
  const float* Wv = (const float*)d_in[26];
  const float* Wo = (const float*)d_in[27];
  const float* ln_w = (const float*)d_in[28];
  const float* ln_b = (const float*)d_in[29];

  // ---- ws layout (total 113,246,208 B = 108 MiB) ----
  char* ws = (char*)d_ws;
  u16* WOB  = (u16*)(ws + 0);                 // 8 MB, live to end
  u16* WRB  = (u16*)(ws + 8388608);           // 8 MB, dead after r-GEMM
  u16* WKB  = (u16*)(ws + 16777216);          // 8 MB
  u16* WVB  = (u16*)(ws + 25165824);          // 8 MB
  u16* WCAT = (u16*)(ws + 33554432);          // 640x2048 bf16 = 2.5 MB
  u16* B2W  = (u16*)(ws + 36175872);          // 2048x128
  u16* B2A  = (u16*)(ws + 36700160);
  u16* B2V  = (u16*)(ws + 37224448);
  u16* B2G  = (u16*)(ws + 37748736);          // 2048x256
  u16* PBUF = (u16*)(ws + 38797312);          // 4096x640 bf16 = 5 MB, dead after stage-2
  u16* RB   = (u16*)(ws + 44040192);          // 16 MB bf16, live to post2
  u16* KB   = (u16*)(ws + 60817408);          // 16 MB (k -> kf in place)
  u16* VB   = (u16*)(ws + 77594624);          // 16 MB (v -> vf in place)
  u16* YB   = (u16*)(ws + 94371840);          // 16 MB bf16, scan -> post2
  float* WKVS = (float*)(ws + 111149056);     // 2 MB f32 scan state out
  float* DEC  = (float*)(ws + 8388608);       // 32 MB f32, overlays dead WRB..PBUF (post1 -> scan)
  u16* AO   = (u16*)(ws + 8388608);           // 16 MB bf16, overlays dead DEC (post2 -> final GEMM)

  // ---- d_out scratch (regions dead before their final write) ----
  float* out       = (float*)d_out;
  float* shift_out = out + 8388608;
  float* wkv_out   = out + 8396800;
  float* vf_out    = out + 8921088;
  u16* WINb = (u16*)d_out;                        // 16 MB in OUT region (dead after post1)
  u16* AINb = (u16*)((char*)d_out + 16777216);    // 16 MB in OUT region (dead after scan)
  u16* VINb = (u16*)((char*)d_out + 35684352);    // 16 MB in VF region (dead after scan)
  u16* GB   = (u16*)((char*)d_out + 52461568);    // 16 MB in VF region (dead after post2)

  // weight casts
  k_cast<<<4096, 256, 0, stream>>>(Wr, WRB, 4194304);
  k_cast<<<4096, 256, 0, stream>>>(Wk, WKB, 4194304);
  k_cast<<<4096, 256, 0, stream>>>(Wv, WVB, 4194304);
  k_cast<<<4096, 256, 0, stream>>>(Wo, WOB, 4194304);

  // stage-1 fused weight (640x2048): rows [0,128)=w1^T pad, [128,256)=a1^T, [256,384)=v1^T, [384,640)=g1^T
  k_tpad<<<1024, 256, 0, stream>>>(w1, WCAT,            2048,  96, 2048, 128);
  k_tpad<<<1024, 256, 0, stream>>>(a1, WCAT + 128*2048, 2048,  96, 2048, 128);
  k_tpad<<<1024, 256, 0, stream>>>(v1, WCAT + 256*2048, 2048,  64, 2048, 128);
  k_tpad<<<2048, 256, 0, stream>>>(g1, WCAT + 384*2048, 2048, 256, 2048, 256);
  // stage-2 weights (2048 x Kpad)
  k_tpad<<<1024, 256, 0, stream>>>(w2, B2W,  96, 2048, 128, 2048);
  k_tpad<<<1024, 256, 0, stream>>>(a2, B2A,  96, 2048, 128, 2048);
  k_tpad<<<1024, 256, 0, stream>>>(v2, B2V,  64, 2048, 128, 2048);
  k_tpad<<<2048, 256, 0, stream>>>(g2, B2G, 256, 2048, 256, 2048);

  // big GEMMs with fused token-shift mixing (bf16 out)
  k_gemm<1,1><<<dim3(16,32), 256, 0, stream>>>(nullptr, x, shift_in, x_r, x_r, x_r, x_r,
                                               WRB, nullptr, RB, 2048, 0, 2048, 2048);
  k_gemm<1,1><<<dim3(16,32), 256, 0, stream>>>(nullptr, x, shift_in, x_k, x_k, x_k, x_k,
                                               WKB, nullptr, KB, 2048, 0, 2048, 2048);
  k_gemm<1,1><<<dim3(16,32), 256, 0, stream>>>(nullptr, x, shift_in, x_v, x_v, x_v, x_v,
                                               WVB, nullptr, VB, 2048, 0, 2048, 2048);

  // fused stage-1 (per-col-tile A/mix select; tanh / id / id / sigmoid epilogue)
  k_gemm<1,2><<<dim3(5,32), 256, 0, stream>>>(nullptr, x, shift_in, x_w, x_a, x_v, x_g,
                                              WCAT, nullptr, PBUF, 2048, 0, 2048, 640);

  // stage-2 GEMMs (bf16 out into d_out scratch)
  k_gemm<0,1><<<dim3(16,32), 256, 0, stream>>>(PBUF+0,   nullptr,nullptr,nullptr,nullptr,nullptr,nullptr,
                                               B2W, nullptr, WINb, 128, 640, 128, 2048);
  k_gemm<0,1><<<dim3(16,32), 256, 0, stream>>>(PBUF+128, nullptr,nullptr,nullptr,nullptr,nullptr,nullptr,
                                               B2A, nullptr, AINb, 128, 640, 128, 2048);
  k_gemm<0,1><<<dim3(16,32), 256, 0, stream>>>(PBUF+256, nullptr,nullptr,nullptr,nullptr,nullptr,nullptr,
                                               B2V, nullptr, VINb, 128, 640, 128, 2048);
  k_gemm<0,1><<<dim3(16,32), 256, 0, stream>>>(PBUF+384, nullptr,nullptr,nullptr,nullptr,nullptr,nullptr,
                                               B2G, nullptr, GB,   256, 640, 256, 2048);

  // elementwise post: k->kf (in place), v->vf (in place), decay->DEC, kk->VINb, b=kk*a->AINb
  k_post1<<<32768, 256, 0, stream>>>(KB, VB, WINb, AINb, VINb, v_first,
                                     w0, a0, v0, k_k, k_a, DEC);

  // sequential WKV scan
  k_scan<<<256, 128, 0, stream>>>(RB, DEC, KB, VB, VINb, AINb, wkv_in, YB, WKVS);

  // groupnorm + bonus + gate
  k_post2<<<32768, 256, 0, stream>>>(YB, RB, KB, VB, GB, r_k, ln_w, ln_b, AO);

  // final GEMM -> out (f32); clobbers WINb/AINb scratch (dead)
  k_gemm<0,0><<<dim3(16,32), 256, 0, stream>>>(AO, nullptr,nullptr,nullptr,nullptr,nullptr,nullptr,
                                               WOB, out, nullptr, 2048, 2048, 2048, 2048);

  // small outputs last (vf copy clobbers VINb/GB scratch — dead by now)
  k_shift<<<8, 256, 0, stream>>>(x, shift_out);
  hipMemcpyAsync(wkv_out, WKVS, 2097152, hipMemcpyDeviceToDevice, stream);
  hipMemcpyAsync(vf_out, v_first, 33554432, hipMemcpyDeviceToDevice, stream);
}

// Round 3
// 1260.866 us; speedup vs baseline: 1.3194x; 1.3194x over previous
//
#include <hip/hip_runtime.h>
#include <stdint.h>

typedef unsigned short u16;
typedef unsigned int u32;
typedef __attribute__((ext_vector_type(8))) short short8;
typedef __attribute__((ext_vector_type(4))) float f32x4;

#define BB 4
#define TT 1024
#define CC 2048

// ---------- helpers ----------
__device__ __forceinline__ u16 f2bf(float f){
  union { float f; u32 u; } v; v.f = f;
  return (u16)((v.u + 0x7FFFu + ((v.u >> 16) & 1u)) >> 16);
}
__device__ __forceinline__ float bf2f(u16 h){
  union { u32 u; float f; } v; v.u = ((u32)h) << 16; return v.f;
}

__device__ __forceinline__ void gload16(const void* g, void* s){
  __builtin_amdgcn_global_load_lds((const __attribute__((address_space(1))) u32*)g,
                                   (__attribute__((address_space(3))) u32*)s, 16, 0, 0);
}

__device__ __forceinline__ float wave_sum64(float x){
  #pragma unroll
  for (int m = 1; m < 64; m <<= 1) x += __shfl_xor(x, m, 64);
  return x;
}

// ---------- cast f32 -> bf16 ----------
__global__ __launch_bounds__(256) void k_cast(const float* __restrict__ in, u16* __restrict__ out, int n){
  int i = (blockIdx.x*256 + threadIdx.x)*4;
  if (i >= n) return;
  float4 v = *(const float4*)&in[i];
  *(ushort4*)&out[i] = make_ushort4(f2bf(v.x), f2bf(v.y), f2bf(v.z), f2bf(v.w));
}

// ---------- transpose + pad: in (R,S) f32 -> out (Spad, Rpad) bf16, out[s][r]=in[r][s] ----------
__global__ __launch_bounds__(256) void k_tpad(const float* __restrict__ in, u16* __restrict__ out,
                                              int R, int S, int Rpad, int Spad){
  int idx = blockIdx.x*256 + threadIdx.x;
  if (idx >= Rpad*Spad) return;
  int s = idx / Rpad, r = idx - s*Rpad;
  float v = (s < S && r < R) ? in[(size_t)r*S + s] : 0.f;
  out[idx] = f2bf(v);
}

// ---------- GEMM: C[M,N] = A[M,K](bf16) * Bt[N,K]^T(bf16) ----------
template<int AMODE, int EPI>
__global__ __launch_bounds__(256) void k_gemm(
  const u16* __restrict__ Abf,
  const float* __restrict__ xg, const float* __restrict__ shiftg,
  const float* __restrict__ mx0, const float* __restrict__ mx1,
  const float* __restrict__ mx2, const float* __restrict__ mx3,
  const u16* __restrict__ Bt, float* __restrict__ Cf, u16* __restrict__ Cb,
  int K, int lda, int ldb, int ldc)
{
  __shared__ alignas(16) u16 sA[128*32];
  __shared__ alignas(16) u16 sB[128*32];
  const int tid = threadIdx.x;
  const int wv = tid >> 6, ln = tid & 63;
  const int bx = blockIdx.x;
  const int row0 = blockIdx.y * 128, col0 = bx * 128;
  const int wr = wv >> 1, wc = wv & 1;
  const float* mixv = nullptr;
  if (AMODE == 1) mixv = (bx==0) ? mx0 : (bx==1) ? mx1 : (bx==2) ? mx2 : mx3;

  f32x4 acc[4][4] = {};
  const int ob0 = wv*2048;
  const int o0  = ob0 + ln*16;
  const int rA0 = o0 >> 6;
  const int ke0 = (o0 & 63) >> 1;
  const int ar  = tid >> 2;
  const int akc = (tid & 3) * 8;

  for (int k0 = 0; k0 < K; k0 += 32){
    __syncthreads();
    if (AMODE == 0){
      gload16(&Abf[(size_t)(row0 + rA0     )*lda + k0 + ke0], (void*)((char*)sA + ob0));
      gload16(&Abf[(size_t)(row0 + rA0 + 16)*lda + k0 + ke0], (void*)((char*)sA + ob0 + 1024));
    }
    gload16(&Bt[(size_t)(col0 + rA0     )*ldb + k0 + ke0], (void*)((char*)sB + ob0));
    gload16(&Bt[(size_t)(col0 + rA0 + 16)*ldb + k0 + ke0], (void*)((char*)sB + ob0 + 1024));
    if (AMODE == 1){
      float4 m0 = *(const float4*)&mixv[k0 + akc];
      float4 m1 = *(const float4*)&mixv[k0 + akc + 4];
      #pragma unroll
      for (int it = 0; it < 2; ++it){
        int r = ar + it*64;
        int gr = row0 + r;
        size_t xo = (size_t)gr*CC + k0 + akc;
        float4 c0 = *(const float4*)&xg[xo];
        float4 c1 = *(const float4*)&xg[xo + 4];
        const float* pp = ((gr & (TT-1)) == 0) ? &shiftg[(size_t)(gr >> 10)*CC + k0 + akc]
                                               : &xg[xo - CC];
        float4 p0 = *(const float4*)&pp[0];
        float4 p1 = *(const float4*)&pp[4];
        short8 vv;
        vv[0] = (short)f2bf(c0.x + (p0.x - c0.x)*m0.x);
        vv[1] = (short)f2bf(c0.y + (p0.y - c0.y)*m0.y);
        vv[2] = (short)f2bf(c0.z + (p0.z - c0.z)*m0.z);
        vv[3] = (short)f2bf(c0.w + (p0.w - c0.w)*m0.w);
        vv[4] = (short)f2bf(c1.x + (p1.x - c1.x)*m1.x);
        vv[5] = (short)f2bf(c1.y + (p1.y - c1.y)*m1.y);
        vv[6] = (short)f2bf(c1.z + (p1.z - c1.z)*m1.z);
        vv[7] = (short)f2bf(c1.w + (p1.w - c1.w)*m1.w);
        *(short8*)&sA[r*32 + akc] = vv;
      }
    }
    __syncthreads();
    short8 aF[4], bF[4];
    #pragma unroll
    for (int m=0;m<4;m++) aF[m] = *(const short8*)&sA[(wr*64 + m*16 + (ln&15))*32 + (ln>>4)*8];
    #pragma unroll
    for (int n=0;n<4;n++) bF[n] = *(const short8*)&sB[(wc*64 + n*16 + (ln&15))*32 + (ln>>4)*8];
    #pragma unroll
    for (int m=0;m<4;m++)
      #pragma unroll
      for (int n=0;n<4;n++)
        acc[m][n] = __builtin_amdgcn_mfma_f32_16x16x32_bf16(aF[m], bF[n], acc[m][n], 0,0,0);
  }

  const int cr = (ln >> 4) * 4, ccol = ln & 15;
  #pragma unroll
  for (int m=0;m<4;m++){
    #pragma unroll
    for (int n=0;n<4;n++){
      int gc = col0 + wc*64 + n*16 + ccol;
      #pragma unroll
      for (int j=0;j<4;j++){
        int gr = row0 + wr*64 + m*16 + cr + j;
        float v = acc[m][n][j];
        if (EPI == 0){
          Cf[(size_t)gr*ldc + gc] = v;
        } else if (EPI == 1){
          Cb[(size_t)gr*ldc + gc] = f2bf(v);
        } else {
          if (bx == 0) v = tanhf(v);
          else if (bx >= 3) v = 1.f/(1.f + expf(-v));
          Cb[(size_t)gr*ldc + gc] = f2bf(v);
        }
      }
    }
  }
}

// ---------- post1 ----------
__global__ __launch_bounds__(256) void k_post1(
  u16* __restrict__ kb, u16* __restrict__ vb, const u16* __restrict__ winb,
  u16* __restrict__ ainb, u16* __restrict__ vinb,
  const float* __restrict__ vfirst,
  const float* __restrict__ w0, const float* __restrict__ a0, const float* __restrict__ v0,
  const float* __restrict__ kkv, const float* __restrict__ kav,
  float* __restrict__ dec)
{
  int grp = blockIdx.x*4 + (threadIdx.x >> 6);
  int n = threadIdx.x & 63;
  int i = grp >> 5, h = grp & 31;
  int c = h*64 + n;
  size_t idx = (size_t)i*CC + c;
  float k  = bf2f(kb[idx]),  v = bf2f(vb[idx]);
  float wi = bf2f(winb[idx]), ai = bf2f(ainb[idx]), vi = bf2f(vinb[idx]);
  float vf = vfirst[idx];
  float a  = 1.f/(1.f + expf(-(a0[c] + ai)));
  float z  = -(w0[c] + wi);
  float sp = (z > 15.f) ? z : log1pf(expf(z));
  float decay = expf(-expf(-sp - 0.5f));
  float vg = 1.f/(1.f + expf(-(v0[c] + vi)));
  float vfin = v + (vf - v)*vg;
  float kkr = k * kkv[c];
  float ss = wave_sum64(kkr*kkr);
  float kkn = kkr / fmaxf(sqrtf(ss), 1e-12f);
  float kfin = k * (1.f + (a - 1.f)*kav[c]);
  kb[idx] = f2bf(kfin);
  vb[idx] = f2bf(vfin);
  dec[idx] = decay;
  vinb[idx] = f2bf(kkn);
  ainb[idx] = f2bf(kkn * a);
}

// ---------- WKV scan: 512 blocks = 128 (b,h) x 4 row-quarters; 64 threads (1 wave) ----------
// Thread (vloc, quad): owns state S[q4*16+vloc][quad*16 .. +15] in 16 registers.
// Chunked (8 steps) double-buffered LDS staging; global loads issued a full chunk ahead.
__global__ __launch_bounds__(64) void k_scan(
  const u16* __restrict__ rb, const float* __restrict__ wb,
  const u16* __restrict__ kb, const u16* __restrict__ vb,
  const u16* __restrict__ kkb, const u16* __restrict__ bbp,
  const float* __restrict__ wkv_in, u16* __restrict__ yb, float* __restrict__ wkv_out)
{
  const int blk = blockIdx.x;
  const int bh = blk >> 2, q4 = blk & 3;
  const int b = bh >> 5, h = bh & 31;
  const int ln = threadIdx.x;
  const int vloc = ln >> 2, quad = ln & 3;
  const int v = q4*16 + vloc;

  __shared__ float4 sq[2][8][64];   // (w, b, k, r), column-XOR-swizzled by step
  __shared__ float  skk[2][8][64];
  __shared__ float  sv[2][8][16];
  __shared__ u16    sy[8][16];

  float st[16];
  {
    const float* sp = wkv_in + ((size_t)bh*64 + v)*64 + quad*16;
    #pragma unroll
    for (int i=0;i<4;i++) *(float4*)&st[i*4] = *(const float4*)&sp[i*4];
  }

  const int sstep = ln >> 3;        // staging: step 0..7
  const int n8 = (ln & 7)*8;        // staging: col block
  const int n2 = (ln & 7)*2;        // staging: v/y col pair
  const size_t g0 = ((size_t)b*TT)*CC + h*64;

  float4 sw0, sw1; short8 kk_r, b_r, k_r, r_r; float v0r, v1r;

  auto issue = [&](size_t toff){
    size_t o = g0 + toff + (size_t)sstep*CC + n8;
    sw0  = *(const float4*)&wb[o];
    sw1  = *(const float4*)&wb[o+4];
    kk_r = *(const short8*)&kkb[o];
    b_r  = *(const short8*)&bbp[o];
    k_r  = *(const short8*)&kb[o];
    r_r  = *(const short8*)&rb[o];
    ushort2 vv = *(const ushort2*)&vb[g0 + toff + (size_t)sstep*CC + q4*16 + n2];
    v0r = bf2f(vv.x); v1r = bf2f(vv.y);
  };
  auto write_lds = [&](int bi){
    float wv[8]; *(float4*)&wv[0] = sw0; *(float4*)&wv[4] = sw1;
    #pragma unroll
    for (int j=0;j<8;j++){
      sq[bi][sstep][(n8+j)^sstep] = make_float4(wv[j], bf2f((u16)b_r[j]),
                                                bf2f((u16)k_r[j]), bf2f((u16)r_r[j]));
    }
    float kf[8];
    #pragma unroll
    for (int j=0;j<8;j++) kf[j] = bf2f((u16)kk_r[j]);
    *(float4*)&skk[bi][sstep][n8]   = *(const float4*)&kf[0];
    *(float4*)&skk[bi][sstep][n8+4] = *(const float4*)&kf[4];
    *(float2*)&sv[bi][sstep][n2] = make_float2(v0r, v1r);
  };

  issue(0);
  write_lds(0);

  size_t gc = 0;
  for (int c = 0; c < 128; ++c){
    const int bi = c & 1;
    if (c < 127) issue(gc + 8*CC);        // next chunk's loads in flight over this chunk's compute
    __syncthreads();
    #pragma unroll
    for (int s=0; s<8; ++s){
      const float* kkp = &skk[bi][s][quad*16];
      float p = 0.f;
      #pragma unroll
      for (int i=0;i<16;i++) p += st[i]*kkp[i];
      p += __shfl_xor(p, 1); p += __shfl_xor(p, 2);
      const float sa = -p;
      const float vvv = sv[bi][s][vloc];
      float y = 0.f;
      #pragma unroll
      for (int i=0;i<16;i++){
        float4 qq = sq[bi][s][quad*16 + (i^s)];
        float s2 = fmaf(st[i], qq.x, fmaf(sa, qq.y, vvv*qq.z));
        st[i] = s2;
        y = fmaf(s2, qq.w, y);
      }
      y += __shfl_xor(y, 1); y += __shfl_xor(y, 2);
      sy[s][vloc] = f2bf(y);              // 4 lanes same value/addr: benign
    }
    __syncthreads();
    *(ushort2*)&yb[g0 + gc + (size_t)sstep*CC + q4*16 + n2] = *(const ushort2*)&sy[sstep][n2];
    if (c < 127) write_lds(bi^1);
    gc += 8*CC;
  }

  float* wo = wkv_out + ((size_t)bh*64 + v)*64 + quad*16;
  #pragma unroll
  for (int i=0;i<4;i++) *(float4*)&wo[i*4] = *(const float4*)&st[i*4];
}

// ---------- post2 ----------
__global__ __launch_bounds__(256) void k_post2(
  const u16* __restrict__ ybuf, const u16* __restrict__ rbuf,
  const u16* __restrict__ kfb, const u16* __restrict__ vfb,
  const u16* __restrict__ gbuf, const float* __restrict__ rk,
  const float* __restrict__ lnw, const float* __restrict__ lnb, u16* __restrict__ ao)
{
  int grp = blockIdx.x*4 + (threadIdx.x >> 6);
  int n = threadIdx.x & 63;
  int i = grp >> 5, h = grp & 31;
  int c = h*64 + n;
  size_t idx = (size_t)i*CC + c;
  float y = bf2f(ybuf[idx]);
  float s1 = wave_sum64(y);
  float s2 = wave_sum64(y*y);
  float mu = s1 * (1.f/64.f);
  float var = s2 * (1.f/64.f) - mu*mu;
  float yn = (y - mu) * rsqrtf(var + 6.4e-4f) * lnw[c] + lnb[c];
  float rv = bf2f(rbuf[idx]), kv = bf2f(kfb[idx]);
  float s3 = wave_sum64(rv * kv * rk[c]);
  float bonus = s3 * bf2f(vfb[idx]);
  ao[idx] = f2bf((yn + bonus) * bf2f(gbuf[idx]));
}

// ---------- shift_state_out = x[:, -1] ----------
__global__ __launch_bounds__(256) void k_shift(const float* __restrict__ x, float* __restrict__ so){
  int i = blockIdx.x*256 + threadIdx.x;
  int b = i >> 9, c4 = (i & 511)*4;
  *(float4*)&so[(size_t)b*CC + c4] = *(const float4*)&x[((size_t)(b*TT + TT-1))*CC + c4];
}

// ---------- launch ----------
extern "C" void kernel_launch(void* const* d_in, const int* in_sizes, int n_in,
                              void* d_out, int out_size, void* d_ws, size_t ws_size,
                              hipStream_t stream)
{
  const float* x        = (const float*)d_in[0];
  const float* shift_in = (const float*)d_in[1];
  const float* wkv_in   = (const float*)d_in[2];
  const float* v_first  = (const float*)d_in[3];
  const float* x_r = (const float*)d_in[4];
  const float* x_w = (const float*)d_in[5];
  const float* x_k = (const float*)d_in[6];
  const float* x_v = (const float*)d_in[7];
  const float* x_a = (const float*)d_in[8];
  const float* x_g = (const float*)d_in[9];
  const float* w0 = (const float*)d_in[10];
  const float* w1 = (const float*)d_in[11];
  const float* w2 = (const float*)d_in[12];
  const float* a0 = (const float*)d_in[13];
  const float* a1 = (const float*)d_in[14];
  const float* a2 = (const float*)d_in[15];
  const float* v0 = (const float*)d_in[16];
  const float* v1 = (const float*)d_in[17];
  const float* v2 = (const float*)d_in[18];
  const float* g1 = (const float*)d_in[19];
  const float* g2 = (const float*)d_in[20];
  const float* k_k = (const float*)d_in[21];
  const float* k_a = (const float*)d_in[22];
  const float* r_k = (const float*)d_in[23];
  const float* Wr = (const float*)d_in[24];
  const float* Wk = (const float*)d_in[25];
  const float* Wv = (const float*)d_in[26];
  const float* Wo = (const float*)d_in[27];
  const float* ln_w = (const float*)d_in[28];
  const float* ln_b = (const float*)d_in[29];

  // ---- ws layout ----
  char* ws = (char*)d_ws;
  u16* WOB  = (u16*)(ws + 0);
  u16* WRB  = (u16*)(ws + 8388608);
  u16* WKB  = (u16*)(ws + 16777216);
  u16* WVB  = (u16*)(ws + 25165824);
  u16* WCAT = (u16*)(ws + 33554432);
  u16* B2W  = (u16*)(ws + 36175872);
  u16* B2A  = (u16*)(ws + 36700160);
  u16* B2V  = (u16*)(ws + 37224448);
  u16* B2G  = (u16*)(ws + 37748736);
  u16* PBUF = (u16*)(ws + 38797312);
  u16* RB   = (u16*)(ws + 44040192);
  u16* KB   = (u16*)(ws + 60817408);
  u16* VB   = (u16*)(ws + 77594624);
  u16* YB   = (u16*)(ws + 94371840);
  float* DEC  = (float*)(ws + 8388608);     // overlays dead WRB..PBUF (post1 -> scan)
  u16* AO   = (u16*)(ws + 8388608);         // overlays dead DEC (post2 -> final GEMM)

  // ---- d_out scratch ----
  float* out       = (float*)d_out;
  float* shift_out = out + 8388608;
  float* wkv_out   = out + 8396800;
  float* vf_out    = out + 8921088;
  u16* WINb = (u16*)d_out;
  u16* AINb = (u16*)((char*)d_out + 16777216);
  u16* VINb = (u16*)((char*)d_out + 35684352);
  u16* GB   = (u16*)((char*)d_out + 52461568);

  // weight casts
  k_cast<<<4096, 256, 0, stream>>>(Wr, WRB, 4194304);
  k_cast<<<4096, 256, 0, stream>>>(Wk, WKB, 4194304);
  k_cast<<<4096, 256, 0, stream>>>(Wv, WVB, 4194304);
  k_cast<<<4096, 256, 0, stream>>>(Wo, WOB, 4194304);

  // stage-1 fused weight + stage-2 weights
  k_tpad<<<1024, 256, 0, stream>>>(w1, WCAT,            2048,  96, 2048, 128);
  k_tpad<<<1024, 256, 0, stream>>>(a1, WCAT + 128*2048, 2048,  96, 2048, 128);
  k_tpad<<<1024, 256, 0, stream>>>(v1, WCAT + 256*2048, 2048,  64, 2048, 128);
  k_tpad<<<2048, 256, 0, stream>>>(g1, WCAT + 384*2048, 2048, 256, 2048, 256);
  k_tpad<<<1024, 256, 0, stream>>>(w2, B2W,  96, 2048, 128, 2048);
  k_tpad<<<1024, 256, 0, stream>>>(a2, B2A,  96, 2048, 128, 2048);
  k_tpad<<<1024, 256, 0, stream>>>(v2, B2V,  64, 2048, 128, 2048);
  k_tpad<<<2048, 256, 0, stream>>>(g2, B2G, 256, 2048, 256, 2048);

  // big GEMMs with fused token-shift mixing
  k_gemm<1,1><<<dim3(16,32), 256, 0, stream>>>(nullptr, x, shift_in, x_r, x_r, x_r, x_r,
                                               WRB, nullptr, RB, 2048, 0, 2048, 2048);
  k_gemm<1,1><<<dim3(16,32), 256, 0, stream>>>(nullptr, x, shift_in, x_k, x_k, x_k, x_k,
                                               WKB, nullptr, KB, 2048, 0, 2048, 2048);
  k_gemm<1,1><<<dim3(16,32), 256, 0, stream>>>(nullptr, x, shift_in, x_v, x_v, x_v, x_v,
                                               WVB, nullptr, VB, 2048, 0, 2048, 2048);

  // fused stage-1
  k_gemm<1,2><<<dim3(5,32), 256, 0, stream>>>(nullptr, x, shift_in, x_w, x_a, x_v, x_g,
                                              WCAT, nullptr, PBUF, 2048, 0, 2048, 640);

  // stage-2 GEMMs
  k_gemm<0,1><<<dim3(16,32), 256, 0, stream>>>(PBUF+0,   nullptr,nullptr,nullptr,nullptr,nullptr,nullptr,
                                               B2W, nullptr, WINb, 128, 640, 128, 2048);
  k_gemm<0,1><<<dim3(16,32), 256, 0, stream>>>(PBUF+128, nullptr,nullptr,nullptr,nullptr,nullptr,nullptr,
                                               B2A, nullptr, AINb, 128, 640, 128, 2048);
  k_gemm<0,1><<<dim3(16,32), 256, 0, stream>>>(PBUF+256, nullptr,nullptr,nullptr,nullptr,nullptr,nullptr,
                                               B2V, nullptr, VINb, 128, 640, 128, 2048);
  k_gemm<0,1><<<dim3(16,32), 256, 0, stream>>>(PBUF+384, nullptr,nullptr,nullptr,nullptr,nullptr,nullptr,
                                               B2G, nullptr, GB,   256, 640, 256, 2048);

  // elementwise post
  k_post1<<<32768, 256, 0, stream>>>(KB, VB, WINb, AINb, VINb, v_first,
                                     w0, a0, v0, k_k, k_a, DEC);

  // sequential WKV scan (writes wkv_out directly)
  k_scan<<<512, 64, 0, stream>>>(RB, DEC, KB, VB, VINb, AINb, wkv_in, YB, wkv_out);

  // groupnorm + bonus + gate
  k_post2<<<32768, 256, 0, stream>>>(YB, RB, KB, VB, GB, r_k, ln_w, ln_b, AO);

  // final GEMM -> out
  k_gemm<0,0><<<dim3(16,32), 256, 0, stream>>>(AO, nullptr,nullptr,nullptr,nullptr,nullptr,nullptr,
                                               WOB, out, nullptr, 2048, 2048, 2048, 2048);

  // small outputs last
  k_shift<<<8, 256, 0, stream>>>(x, shift_out);
  hipMemcpyAsync(vf_out, v_first, 33554432, hipMemcpyDeviceToDevice, stream);
}

// Round 4
// 1026.111 us; speedup vs baseline: 1.6213x; 1.2288x over previous
//
#include <hip/hip_runtime.h>
#include <stdint.h>

typedef unsigned short u16;
typedef unsigned int u32;
typedef __attribute__((ext_vector_type(8))) short short8;
typedef __attribute__((ext_vector_type(4))) float f32x4;

#define BB 4
#define TT 1024
#define CC 2048

// ---------- helpers ----------
__device__ __forceinline__ u16 f2bf(float f){
  union { float f; u32 u; } v; v.f = f;
  return (u16)((v.u + 0x7FFFu + ((v.u >> 16) & 1u)) >> 16);
}
__device__ __forceinline__ float bf2f(u16 h){
  union { u32 u; float f; } v; v.u = ((u32)h) << 16; return v.f;
}

__device__ __forceinline__ void gload16(const void* g, void* s){
  __builtin_amdgcn_global_load_lds((const __attribute__((address_space(1))) u32*)g,
                                   (__attribute__((address_space(3))) u32*)s, 16, 0, 0);
}

__device__ __forceinline__ float wave_sum64(float x){
  #pragma unroll
  for (int m = 1; m < 64; m <<= 1) x += __shfl_xor(x, m, 64);
  return x;
}

// DPP row (16-lane) rotate-add reduction — VALU-only, no LDS pipe
template<int N>
__device__ __forceinline__ float ror_add(float x){
  int t = __builtin_amdgcn_update_dpp(0, __builtin_bit_cast(int, x), 0x120 | N, 0xF, 0xF, false);
  return x + __builtin_bit_cast(float, t);
}
__device__ __forceinline__ float red16(float x){
  x = ror_add<8>(x); x = ror_add<4>(x); x = ror_add<2>(x); x = ror_add<1>(x);
  return x;
}

// ---------- cast f32 -> bf16 ----------
__global__ __launch_bounds__(256) void k_cast(const float* __restrict__ in, u16* __restrict__ out, int n){
  int i = (blockIdx.x*256 + threadIdx.x)*4;
  if (i >= n) return;
  float4 v = *(const float4*)&in[i];
  *(ushort4*)&out[i] = make_ushort4(f2bf(v.x), f2bf(v.y), f2bf(v.z), f2bf(v.w));
}

// ---------- transpose + pad ----------
__global__ __launch_bounds__(256) void k_tpad(const float* __restrict__ in, u16* __restrict__ out,
                                              int R, int S, int Rpad, int Spad){
  int idx = blockIdx.x*256 + threadIdx.x;
  if (idx >= Rpad*Spad) return;
  int s = idx / Rpad, r = idx - s*Rpad;
  float v = (s < S && r < R) ? in[(size_t)r*S + s] : 0.f;
  out[idx] = f2bf(v);
}

// ---------- GEMM: C[M,N] = A[M,K](bf16) * Bt[N,K]^T(bf16) ----------
template<int AMODE, int EPI>
__global__ __launch_bounds__(256) void k_gemm(
  const u16* __restrict__ Abf,
  const float* __restrict__ xg, const float* __restrict__ shiftg,
  const float* __restrict__ mx0, const float* __restrict__ mx1,
  const float* __restrict__ mx2, const float* __restrict__ mx3,
  const u16* __restrict__ Bt, float* __restrict__ Cf, u16* __restrict__ Cb,
  int K, int lda, int ldb, int ldc)
{
  __shared__ alignas(16) u16 sA[128*32];
  __shared__ alignas(16) u16 sB[128*32];
  const int tid = threadIdx.x;
  const int wv = tid >> 6, ln = tid & 63;
  const int bx = blockIdx.x;
  const int row0 = blockIdx.y * 128, col0 = bx * 128;
  const int wr = wv >> 1, wc = wv & 1;
  const float* mixv = nullptr;
  if (AMODE == 1) mixv = (bx==0) ? mx0 : (bx==1) ? mx1 : (bx==2) ? mx2 : mx3;

  f32x4 acc[4][4] = {};
  const int ob0 = wv*2048;
  const int o0  = ob0 + ln*16;
  const int rA0 = o0 >> 6;
  const int ke0 = (o0 & 63) >> 1;
  const int ar  = tid >> 2;
  const int akc = (tid & 3) * 8;

  for (int k0 = 0; k0 < K; k0 += 32){
    __syncthreads();
    if (AMODE == 0){
      gload16(&Abf[(size_t)(row0 + rA0     )*lda + k0 + ke0], (void*)((char*)sA + ob0));
      gload16(&Abf[(size_t)(row0 + rA0 + 16)*lda + k0 + ke0], (void*)((char*)sA + ob0 + 1024));
    }
    gload16(&Bt[(size_t)(col0 + rA0     )*ldb + k0 + ke0], (void*)((char*)sB + ob0));
    gload16(&Bt[(size_t)(col0 + rA0 + 16)*ldb + k0 + ke0], (void*)((char*)sB + ob0 + 1024));
    if (AMODE == 1){
      float4 m0 = *(const float4*)&mixv[k0 + akc];
      float4 m1 = *(const float4*)&mixv[k0 + akc + 4];
      #pragma unroll
      for (int it = 0; it < 2; ++it){
        int r = ar + it*64;
        int gr = row0 + r;
        size_t xo = (size_t)gr*CC + k0 + akc;
        float4 c0 = *(const float4*)&xg[xo];
        float4 c1 = *(const float4*)&xg[xo + 4];
        const float* pp = ((gr & (TT-1)) == 0) ? &shiftg[(size_t)(gr >> 10)*CC + k0 + akc]
                                               : &xg[xo - CC];
        float4 p0 = *(const float4*)&pp[0];
        float4 p1 = *(const float4*)&pp[4];
        short8 vv;
        vv[0] = (short)f2bf(c0.x + (p0.x - c0.x)*m0.x);
        vv[1] = (short)f2bf(c0.y + (p0.y - c0.y)*m0.y);
        vv[2] = (short)f2bf(c0.z + (p0.z - c0.z)*m0.z);
        vv[3] = (short)f2bf(c0.w + (p0.w - c0.w)*m0.w);
        vv[4] = (short)f2bf(c1.x + (p1.x - c1.x)*m1.x);
        vv[5] = (short)f2bf(c1.y + (p1.y - c1.y)*m1.y);
        vv[6] = (short)f2bf(c1.z + (p1.z - c1.z)*m1.z);
        vv[7] = (short)f2bf(c1.w + (p1.w - c1.w)*m1.w);
        *(short8*)&sA[r*32 + akc] = vv;
      }
    }
    __syncthreads();
    short8 aF[4], bF[4];
    #pragma unroll
    for (int m=0;m<4;m++) aF[m] = *(const short8*)&sA[(wr*64 + m*16 + (ln&15))*32 + (ln>>4)*8];
    #pragma unroll
    for (int n=0;n<4;n++) bF[n] = *(const short8*)&sB[(wc*64 + n*16 + (ln&15))*32 + (ln>>4)*8];
    #pragma unroll
    for (int m=0;m<4;m++)
      #pragma unroll
      for (int n=0;n<4;n++)
        acc[m][n] = __builtin_amdgcn_mfma_f32_16x16x32_bf16(aF[m], bF[n], acc[m][n], 0,0,0);
  }

  const int cr = (ln >> 4) * 4, ccol = ln & 15;
  #pragma unroll
  for (int m=0;m<4;m++){
    #pragma unroll
    for (int n=0;n<4;n++){
      int gc = col0 + wc*64 + n*16 + ccol;
      #pragma unroll
      for (int j=0;j<4;j++){
        int gr = row0 + wr*64 + m*16 + cr + j;
        float v = acc[m][n][j];
        if (EPI == 0){
          Cf[(size_t)gr*ldc + gc] = v;
        } else if (EPI == 1){
          Cb[(size_t)gr*ldc + gc] = f2bf(v);
        } else {
          if (bx == 0) v = tanhf(v);
          else if (bx >= 3) v = 1.f/(1.f + expf(-v));
          Cb[(size_t)gr*ldc + gc] = f2bf(v);
        }
      }
    }
  }
}

// ---------- post1: elementwise + kk-normalize (b staged NEGATED for scan) ----------
__global__ __launch_bounds__(256) void k_post1(
  u16* __restrict__ kb, u16* __restrict__ vb, const u16* __restrict__ winb,
  u16* __restrict__ ainb, u16* __restrict__ vinb,
  const float* __restrict__ vfirst,
  const float* __restrict__ w0, const float* __restrict__ a0, const float* __restrict__ v0,
  const float* __restrict__ kkv, const float* __restrict__ kav,
  float* __restrict__ dec)
{
  int grp = blockIdx.x*4 + (threadIdx.x >> 6);
  int n = threadIdx.x & 63;
  int i = grp >> 5, h = grp & 31;
  int c = h*64 + n;
  size_t idx = (size_t)i*CC + c;
  float k  = bf2f(kb[idx]),  v = bf2f(vb[idx]);
  float wi = bf2f(winb[idx]), ai = bf2f(ainb[idx]), vi = bf2f(vinb[idx]);
  float vf = vfirst[idx];
  float a  = 1.f/(1.f + expf(-(a0[c] + ai)));
  float z  = -(w0[c] + wi);
  float sp = (z > 15.f) ? z : log1pf(expf(z));
  float decay = expf(-expf(-sp - 0.5f));
  float vg = 1.f/(1.f + expf(-(v0[c] + vi)));
  float vfin = v + (vf - v)*vg;
  float kkr = k * kkv[c];
  float ss = wave_sum64(kkr*kkr);
  float kkn = kkr / fmaxf(sqrtf(ss), 1e-12f);
  float kfin = k * (1.f + (a - 1.f)*kav[c]);
  kb[idx] = f2bf(kfin);
  vb[idx] = f2bf(vfin);
  dec[idx] = decay;
  vinb[idx] = f2bf(kkn);
  ainb[idx] = f2bf(-(kkn * a));   // pre-negated b for the scan
}

// ---------- WKV scan v3: 1024 blocks = 128 (b,h) x 8 row-octets; 64 threads (1 wave) ----------
// Lane (rg=ln>>4, cg=ln&15): owns S[oct*8+rg*2 .. +1][cg*4 .. +3] in 8 registers.
// Col vectors (w,bneg,k,kk,r) + v loaded straight to registers, double-buffered
// one 4-step chunk ahead. Row reductions via DPP row_ror (VALU-only). No LDS.
#define SCAN_ISSUE(W4,B4,K4,KK4,R4,V2,t0) do {                                   \
  _Pragma("unroll")                                                              \
  for (int s_=0; s_<4; ++s_){                                                    \
    size_t o_ = gc0 + (size_t)((t0)+s_)*CC;                                      \
    W4[s_]  = *(const float4*)&wb[o_];                                           \
    B4[s_]  = *(const ushort4*)&bbp[o_];                                         \
    K4[s_]  = *(const ushort4*)&kb[o_];                                          \
    KK4[s_] = *(const ushort4*)&kkb[o_];                                         \
    R4[s_]  = *(const ushort4*)&rb[o_];                                          \
    V2[s_]  = *(const u32*)&vb[gv0 + (size_t)((t0)+s_)*CC];                      \
  }                                                                              \
} while(0)

#define SCAN_CHUNK(W4,B4,K4,KK4,R4,V2,t0) do {                                   \
  _Pragma("unroll")                                                              \
  for (int s_=0; s_<4; ++s_){                                                    \
    const float w_0=W4[s_].x, w_1=W4[s_].y, w_2=W4[s_].z, w_3=W4[s_].w;          \
    const float b_0=bf2f(B4[s_].x), b_1=bf2f(B4[s_].y),                          \
                b_2=bf2f(B4[s_].z), b_3=bf2f(B4[s_].w);                          \
    const float k_0=bf2f(K4[s_].x), k_1=bf2f(K4[s_].y),                          \
                k_2=bf2f(K4[s_].z), k_3=bf2f(K4[s_].w);                          \
    const float q_0=bf2f(KK4[s_].x), q_1=bf2f(KK4[s_].y),                        \
                q_2=bf2f(KK4[s_].z), q_3=bf2f(KK4[s_].w);                        \
    const float r_0=bf2f(R4[s_].x), r_1=bf2f(R4[s_].y),                          \
                r_2=bf2f(R4[s_].z), r_3=bf2f(R4[s_].w);                          \
    const u32 vpk_ = V2[s_];                                                     \
    const float vv0_ = bf2f((u16)(vpk_ & 0xFFFFu));                              \
    const float vv1_ = bf2f((u16)(vpk_ >> 16));                                  \
    float p0_ = fmaf(st[0][0],q_0, fmaf(st[0][1],q_1, fmaf(st[0][2],q_2, st[0][3]*q_3))); \
    float p1_ = fmaf(st[1][0],q_0, fmaf(st[1][1],q_1, fmaf(st[1][2],q_2, st[1][3]*q_3))); \
    p0_ = red16(p0_); p1_ = red16(p1_);                                          \
    st[0][0] = fmaf(st[0][0],w_0, fmaf(p0_,b_0, vv0_*k_0));                      \
    st[0][1] = fmaf(st[0][1],w_1, fmaf(p0_,b_1, vv0_*k_1));                      \
    st[0][2] = fmaf(st[0][2],w_2, fmaf(p0_,b_2, vv0_*k_2));                      \
    st[0][3] = fmaf(st[0][3],w_3, fmaf(p0_,b_3, vv0_*k_3));                      \
    st[1][0] = fmaf(st[1][0],w_0, fmaf(p1_,b_0, vv1_*k_0));                      \
    st[1][1] = fmaf(st[1][1],w_1, fmaf(p1_,b_1, vv1_*k_1));                      \
    st[1][2] = fmaf(st[1][2],w_2, fmaf(p1_,b_2, vv1_*k_2));                      \
    st[1][3] = fmaf(st[1][3],w_3, fmaf(p1_,b_3, vv1_*k_3));                      \
    float y0_ = fmaf(st[0][0],r_0, fmaf(st[0][1],r_1, fmaf(st[0][2],r_2, st[0][3]*r_3))); \
    float y1_ = fmaf(st[1][0],r_0, fmaf(st[1][1],r_1, fmaf(st[1][2],r_2, st[1][3]*r_3))); \
    y0_ = red16(y0_); y1_ = red16(y1_);                                          \
    if (cg == 0){                                                                \
      u32 pk_ = (u32)f2bf(y0_) | ((u32)f2bf(y1_) << 16);                         \
      *(u32*)&yb[gv0 + (size_t)((t0)+s_)*CC] = pk_;                              \
    }                                                                            \
  }                                                                              \
} while(0)

__global__ __launch_bounds__(64) void k_scan(
  const u16* __restrict__ rb, const float* __restrict__ wb,
  const u16* __restrict__ kb, const u16* __restrict__ vb,
  const u16* __restrict__ kkb, const u16* __restrict__ bbp,
  const float* __restrict__ wkv_in, u16* __restrict__ yb, float* __restrict__ wkv_out)
{
  const int blk = blockIdx.x;
  const int bh = blk >> 3, oct = blk & 7;
  const int b = bh >> 5, h = bh & 31;
  const int ln = threadIdx.x;
  const int rg = ln >> 4;            // row pair group 0..3
  const int cg = ln & 15;            // col group 0..15
  const int row0 = oct*8 + rg*2;
  const int col0 = cg*4;

  float st[2][4];
  {
    const float* sp0 = &wkv_in[((size_t)bh*64 + row0    )*64 + col0];
    const float* sp1 = &wkv_in[((size_t)bh*64 + row0 + 1)*64 + col0];
    float4 a = *(const float4*)sp0, c = *(const float4*)sp1;
    st[0][0]=a.x; st[0][1]=a.y; st[0][2]=a.z; st[0][3]=a.w;
    st[1][0]=c.x; st[1][1]=c.y; st[1][2]=c.z; st[1][3]=c.w;
  }

  const size_t gc0 = ((size_t)b*TT)*CC + h*64 + col0;          // col-data base
  const size_t gv0 = ((size_t)b*TT)*CC + h*64 + row0;          // v / y base

  float4 wA[4], wB[4];
  ushort4 bA[4], kA[4], kkA[4], rA[4];
  ushort4 bB[4], kB[4], kkB[4], rB2[4];
  u32 vA[4], vB[4];

  SCAN_ISSUE(wA, bA, kA, kkA, rA, vA, 0);
  for (int t0 = 0; t0 < TT; t0 += 8){
    SCAN_ISSUE(wB, bB, kB, kkB, rB2, vB, t0 + 4);
    SCAN_CHUNK(wA, bA, kA, kkA, rA, vA, t0);
    if (t0 + 8 < TT) SCAN_ISSUE(wA, bA, kA, kkA, rA, vA, t0 + 8);
    SCAN_CHUNK(wB, bB, kB, kkB, rB2, vB, t0 + 4);
  }

  {
    float* wo0 = &wkv_out[((size_t)bh*64 + row0    )*64 + col0];
    float* wo1 = &wkv_out[((size_t)bh*64 + row0 + 1)*64 + col0];
    *(float4*)wo0 = make_float4(st[0][0], st[0][1], st[0][2], st[0][3]);
    *(float4*)wo1 = make_float4(st[1][0], st[1][1], st[1][2], st[1][3]);
  }
}

// ---------- post2 ----------
__global__ __launch_bounds__(256) void k_post2(
  const u16* __restrict__ ybuf, const u16* __restrict__ rbuf,
  const u16* __restrict__ kfb, const u16* __restrict__ vfb,
  const u16* __restrict__ gbuf, const float* __restrict__ rk,
  const float* __restrict__ lnw, const float* __restrict__ lnb, u16* __restrict__ ao)
{
  int grp = blockIdx.x*4 + (threadIdx.x >> 6);
  int n = threadIdx.x & 63;
  int i = grp >> 5, h = grp & 31;
  int c = h*64 + n;
  size_t idx = (size_t)i*CC + c;
  float y = bf2f(ybuf[idx]);
  float s1 = wave_sum64(y);
  float s2 = wave_sum64(y*y);
  float mu = s1 * (1.f/64.f);
  float var = s2 * (1.f/64.f) - mu*mu;
  float yn = (y - mu) * rsqrtf(var + 6.4e-4f) * lnw[c] + lnb[c];
  float rv = bf2f(rbuf[idx]), kv = bf2f(kfb[idx]);
  float s3 = wave_sum64(rv * kv * rk[c]);
  float bonus = s3 * bf2f(vfb[idx]);
  ao[idx] = f2bf((yn + bonus) * bf2f(gbuf[idx]));
}

// ---------- shift_state_out = x[:, -1] ----------
__global__ __launch_bounds__(256) void k_shift(const float* __restrict__ x, float* __restrict__ so){
  int i = blockIdx.x*256 + threadIdx.x;
  int b = i >> 9, c4 = (i & 511)*4;
  *(float4*)&so[(size_t)b*CC + c4] = *(const float4*)&x[((size_t)(b*TT + TT-1))*CC + c4];
}

// ---------- launch ----------
extern "C" void kernel_launch(void* const* d_in, const int* in_sizes, int n_in,
                              void* d_out, int out_size, void* d_ws, size_t ws_size,
                              hipStream_t stream)
{
  const float* x        = (const float*)d_in[0];
  const float* shift_in = (const float*)d_in[1];
  const float* wkv_in   = (const float*)d_in[2];
  const float* v_first  = (const float*)d_in[3];
  const float* x_r = (const float*)d_in[4];
  const float* x_w = (const float*)d_in[5];
  const float* x_k = (const float*)d_in[6];
  const float* x_v = (const float*)d_in[7];
  const float* x_a = (const float*)d_in[8];
  const float* x_g = (const float*)d_in[9];
  const float* w0 = (const float*)d_in[10];
  const float* w1 = (const float*)d_in[11];
  const float* w2 = (const float*)d_in[12];
  const float* a0 = (const float*)d_in[13];
  const float* a1 = (const float*)d_in[14];
  const float* a2 = (const float*)d_in[15];
  const float* v0 = (const float*)d_in[16];
  const float* v1 = (const float*)d_in[17];
  const float* v2 = (const float*)d_in[18];
  const float* g1 = (const float*)d_in[19];
  const float* g2 = (const float*)d_in[20];
  const float* k_k = (const float*)d_in[21];
  const float* k_a = (const float*)d_in[22];
  const float* r_k = (const float*)d_in[23];
  const float* Wr = (const float*)d_in[24];
  const float* Wk = (const float*)d_in[25];
  const float* Wv = (const float*)d_in[26];
  const float* Wo = (const float*)d_in[27];
  const float* ln_w = (const float*)d_in[28];
  const float* ln_b = (const float*)d_in[29];

  // ---- ws layout ----
  char* ws = (char*)d_ws;
  u16* WOB  = (u16*)(ws + 0);
  u16* WRB  = (u16*)(ws + 8388608);
  u16* WKB  = (u16*)(ws + 16777216);
  u16* WVB  = (u16*)(ws + 25165824);
  u16* WCAT = (u16*)(ws + 33554432);
  u16* B2W  = (u16*)(ws + 36175872);
  u16* B2A  = (u16*)(ws + 36700160);
  u16* B2V  = (u16*)(ws + 37224448);
  u16* B2G  = (u16*)(ws + 37748736);
  u16* PBUF = (u16*)(ws + 38797312);
  u16* RB   = (u16*)(ws + 44040192);
  u16* KB   = (u16*)(ws + 60817408);
  u16* VB   = (u16*)(ws + 77594624);
  u16* YB   = (u16*)(ws + 94371840);
  float* DEC  = (float*)(ws + 8388608);     // overlays dead WRB..PBUF (post1 -> scan)
  u16* AO   = (u16*)(ws + 8388608);         // overlays dead DEC (post2 -> final GEMM)

  // ---- d_out scratch ----
  float* out       = (float*)d_out;
  float* shift_out = out + 8388608;
  float* wkv_out   = out + 8396800;
  float* vf_out    = out + 8921088;
  u16* WINb = (u16*)d_out;
  u16* AINb = (u16*)((char*)d_out + 16777216);
  u16* VINb = (u16*)((char*)d_out + 35684352);
  u16* GB   = (u16*)((char*)d_out + 52461568);

  // weight casts
  k_cast<<<4096, 256, 0, stream>>>(Wr, WRB, 4194304);
  k_cast<<<4096, 256, 0, stream>>>(Wk, WKB, 4194304);
  k_cast<<<4096, 256, 0, stream>>>(Wv, WVB, 4194304);
  k_cast<<<4096, 256, 0, stream>>>(Wo, WOB, 4194304);

  // stage-1 fused weight + stage-2 weights
  k_tpad<<<1024, 256, 0, stream>>>(w1, WCAT,            2048,  96, 2048, 128);
  k_tpad<<<1024, 256, 0, stream>>>(a1, WCAT + 128*2048, 2048,  96, 2048, 128);
  k_tpad<<<1024, 256, 0, stream>>>(v1, WCAT + 256*2048, 2048,  64, 2048, 128);
  k_tpad<<<2048, 256, 0, stream>>>(g1, WCAT + 384*2048, 2048, 256, 2048, 256);
  k_tpad<<<1024, 256, 0, stream>>>(w2, B2W,  96, 2048, 128, 2048);
  k_tpad<<<1024, 256, 0, stream>>>(a2, B2A,  96, 2048, 128, 2048);
  k_tpad<<<1024, 256, 0, stream>>>(v2, B2V,  64, 2048, 128, 2048);
  k_tpad<<<2048, 256, 0, stream>>>(g2, B2G, 256, 2048, 256, 2048);

  // big GEMMs with fused token-shift mixing
  k_gemm<1,1><<<dim3(16,32), 256, 0, stream>>>(nullptr, x, shift_in, x_r, x_r, x_r, x_r,
                                               WRB, nullptr, RB, 2048, 0, 2048, 2048);
  k_gemm<1,1><<<dim3(16,32), 256, 0, stream>>>(nullptr, x, shift_in, x_k, x_k, x_k, x_k,
                                               WKB, nullptr, KB, 2048, 0, 2048, 2048);
  k_gemm<1,1><<<dim3(16,32), 256, 0, stream>>>(nullptr, x, shift_in, x_v, x_v, x_v, x_v,
                                               WVB, nullptr, VB, 2048, 0, 2048, 2048);

  // fused stage-1
  k_gemm<1,2><<<dim3(5,32), 256, 0, stream>>>(nullptr, x, shift_in, x_w, x_a, x_v, x_g,
                                              WCAT, nullptr, PBUF, 2048, 0, 2048, 640);

  // stage-2 GEMMs
  k_gemm<0,1><<<dim3(16,32), 256, 0, stream>>>(PBUF+0,   nullptr,nullptr,nullptr,nullptr,nullptr,nullptr,
                                               B2W, nullptr, WINb, 128, 640, 128, 2048);
  k_gemm<0,1><<<dim3(16,32), 256, 0, stream>>>(PBUF+128, nullptr,nullptr,nullptr,nullptr,nullptr,nullptr,
                                               B2A, nullptr, AINb, 128, 640, 128, 2048);
  k_gemm<0,1><<<dim3(16,32), 256, 0, stream>>>(PBUF+256, nullptr,nullptr,nullptr,nullptr,nullptr,nullptr,
                                               B2V, nullptr, VINb, 128, 640, 128, 2048);
  k_gemm<0,1><<<dim3(16,32), 256, 0, stream>>>(PBUF+384, nullptr,nullptr,nullptr,nullptr,nullptr,nullptr,
                                               B2G, nullptr, GB,   256, 640, 256, 2048);

  // elementwise post
  k_post1<<<32768, 256, 0, stream>>>(KB, VB, WINb, AINb, VINb, v_first,
                                     w0, a0, v0, k_k, k_a, DEC);

  // sequential WKV scan (register-resident, LDS-free)
  k_scan<<<1024, 64, 0, stream>>>(RB, DEC, KB, VB, VINb, AINb, wkv_in, YB, wkv_out);

  // groupnorm + bonus + gate
  k_post2<<<32768, 256, 0, stream>>>(YB, RB, KB, VB, GB, r_k, ln_w, ln_b, AO);

  // final GEMM -> out
  k_gemm<0,0><<<dim3(16,32), 256, 0, stream>>>(AO, nullptr,nullptr,nullptr,nullptr,nullptr,nullptr,
                                               WOB, out, nullptr, 2048, 2048, 2048, 2048);

  // small outputs last
  k_shift<<<8, 256, 0, stream>>>(x, shift_out);
  hipMemcpyAsync(wkv_out, wkv_out, 4, hipMemcpyDeviceToDevice, stream); // no-op keep stream shape
  hipMemcpyAsync(vf_out, v_first, 33554432, hipMemcpyDeviceToDevice, stream);
}

// Round 5
// 910.142 us; speedup vs baseline: 1.8279x; 1.1274x over previous
//
#include <hip/hip_runtime.h>
#include <stdint.h>

typedef unsigned short u16;
typedef unsigned int u32;
typedef __attribute__((ext_vector_type(8))) short short8;
typedef __attribute__((ext_vector_type(4))) float f32x4;

#define BB 4
#define TT 1024
#define CC 2048

// ---------- helpers ----------
__device__ __forceinline__ u16 f2bf(float f){
  union { float f; u32 u; } v; v.f = f;
  return (u16)((v.u + 0x7FFFu + ((v.u >> 16) & 1u)) >> 16);
}
__device__ __forceinline__ float bf2f(u16 h){
  union { u32 u; float f; } v; v.u = ((u32)h) << 16; return v.f;
}

__device__ __forceinline__ void gload16(const void* g, void* s){
  __builtin_amdgcn_global_load_lds((const __attribute__((address_space(1))) u32*)g,
                                   (__attribute__((address_space(3))) u32*)s, 16, 0, 0);
}

__device__ __forceinline__ float wave_sum64(float x){
  #pragma unroll
  for (int m = 1; m < 64; m <<= 1) x += __shfl_xor(x, m, 64);
  return x;
}

// DPP row (16-lane) rotate-add reduction — VALU-only, no LDS pipe
template<int N>
__device__ __forceinline__ float ror_add(float x){
  int t = __builtin_amdgcn_update_dpp(0, __builtin_bit_cast(int, x), 0x120 | N, 0xF, 0xF, false);
  return x + __builtin_bit_cast(float, t);
}
__device__ __forceinline__ float red16(float x){
  x = ror_add<8>(x); x = ror_add<4>(x); x = ror_add<2>(x); x = ror_add<1>(x);
  return x;
}

// ---------- cast f32 -> bf16 ----------
__global__ __launch_bounds__(256) void k_cast(const float* __restrict__ in, u16* __restrict__ out, int n){
  int i = (blockIdx.x*256 + threadIdx.x)*4;
  if (i >= n) return;
  float4 v = *(const float4*)&in[i];
  *(ushort4*)&out[i] = make_ushort4(f2bf(v.x), f2bf(v.y), f2bf(v.z), f2bf(v.w));
}

// ---------- transpose + pad ----------
__global__ __launch_bounds__(256) void k_tpad(const float* __restrict__ in, u16* __restrict__ out,
                                              int R, int S, int Rpad, int Spad){
  int idx = blockIdx.x*256 + threadIdx.x;
  if (idx >= Rpad*Spad) return;
  int s = idx / Rpad, r = idx - s*Rpad;
  float v = (s < S && r < R) ? in[(size_t)r*S + s] : 0.f;
  out[idx] = f2bf(v);
}

// ---------- GEMM: C[M,N] = A[M,K](bf16) * Bt[N,K]^T(bf16) ----------
template<int AMODE, int EPI>
__global__ __launch_bounds__(256) void k_gemm(
  const u16* __restrict__ Abf,
  const float* __restrict__ xg, const float* __restrict__ shiftg,
  const float* __restrict__ mx0, const float* __restrict__ mx1,
  const float* __restrict__ mx2, const float* __restrict__ mx3,
  const u16* __restrict__ Bt, float* __restrict__ Cf, u16* __restrict__ Cb,
  int K, int lda, int ldb, int ldc)
{
  __shared__ alignas(16) u16 sA[128*32];
  __shared__ alignas(16) u16 sB[128*32];
  const int tid = threadIdx.x;
  const int wv = tid >> 6, ln = tid & 63;
  const int bx = blockIdx.x;
  const int row0 = blockIdx.y * 128, col0 = bx * 128;
  const int wr = wv >> 1, wc = wv & 1;
  const float* mixv = nullptr;
  if (AMODE == 1) mixv = (bx==0) ? mx0 : (bx==1) ? mx1 : (bx==2) ? mx2 : mx3;

  f32x4 acc[4][4] = {};
  const int ob0 = wv*2048;
  const int o0  = ob0 + ln*16;
  const int rA0 = o0 >> 6;
  const int ke0 = (o0 & 63) >> 1;
  const int ar  = tid >> 2;
  const int akc = (tid & 3) * 8;

  for (int k0 = 0; k0 < K; k0 += 32){
    __syncthreads();
    if (AMODE == 0){
      gload16(&Abf[(size_t)(row0 + rA0     )*lda + k0 + ke0], (void*)((char*)sA + ob0));
      gload16(&Abf[(size_t)(row0 + rA0 + 16)*lda + k0 + ke0], (void*)((char*)sA + ob0 + 1024));
    }
    gload16(&Bt[(size_t)(col0 + rA0     )*ldb + k0 + ke0], (void*)((char*)sB + ob0));
    gload16(&Bt[(size_t)(col0 + rA0 + 16)*ldb + k0 + ke0], (void*)((char*)sB + ob0 + 1024));
    if (AMODE == 1){
      float4 m0 = *(const float4*)&mixv[k0 + akc];
      float4 m1 = *(const float4*)&mixv[k0 + akc + 4];
      #pragma unroll
      for (int it = 0; it < 2; ++it){
        int r = ar + it*64;
        int gr = row0 + r;
        size_t xo = (size_t)gr*CC + k0 + akc;
        float4 c0 = *(const float4*)&xg[xo];
        float4 c1 = *(const float4*)&xg[xo + 4];
        const float* pp = ((gr & (TT-1)) == 0) ? &shiftg[(size_t)(gr >> 10)*CC + k0 + akc]
                                               : &xg[xo - CC];
        float4 p0 = *(const float4*)&pp[0];
        float4 p1 = *(const float4*)&pp[4];
        short8 vv;
        vv[0] = (short)f2bf(c0.x + (p0.x - c0.x)*m0.x);
        vv[1] = (short)f2bf(c0.y + (p0.y - c0.y)*m0.y);
        vv[2] = (short)f2bf(c0.z + (p0.z - c0.z)*m0.z);
        vv[3] = (short)f2bf(c0.w + (p0.w - c0.w)*m0.w);
        vv[4] = (short)f2bf(c1.x + (p1.x - c1.x)*m1.x);
        vv[5] = (short)f2bf(c1.y + (p1.y - c1.y)*m1.y);
        vv[6] = (short)f2bf(c1.z + (p1.z - c1.z)*m1.z);
        vv[7] = (short)f2bf(c1.w + (p1.w - c1.w)*m1.w);
        *(short8*)&sA[r*32 + akc] = vv;
      }
    }
    __syncthreads();
    short8 aF[4], bF[4];
    #pragma unroll
    for (int m=0;m<4;m++) aF[m] = *(const short8*)&sA[(wr*64 + m*16 + (ln&15))*32 + (ln>>4)*8];
    #pragma unroll
    for (int n=0;n<4;n++) bF[n] = *(const short8*)&sB[(wc*64 + n*16 + (ln&15))*32 + (ln>>4)*8];
    #pragma unroll
    for (int m=0;m<4;m++)
      #pragma unroll
      for (int n=0;n<4;n++)
        acc[m][n] = __builtin_amdgcn_mfma_f32_16x16x32_bf16(aF[m], bF[n], acc[m][n], 0,0,0);
  }

  const int cr = (ln >> 4) * 4, ccol = ln & 15;
  #pragma unroll
  for (int m=0;m<4;m++){
    #pragma unroll
    for (int n=0;n<4;n++){
      int gc = col0 + wc*64 + n*16 + ccol;
      #pragma unroll
      for (int j=0;j<4;j++){
        int gr = row0 + wr*64 + m*16 + cr + j;
        float v = acc[m][n][j];
        if (EPI == 0){
          Cf[(size_t)gr*ldc + gc] = v;
        } else if (EPI == 1){
          Cb[(size_t)gr*ldc + gc] = f2bf(v);
        } else {
          if (bx == 0) v = tanhf(v);
          else if (bx >= 3) v = 1.f/(1.f + expf(-v));
          Cb[(size_t)gr*ldc + gc] = f2bf(v);
        }
      }
    }
  }
}

// ---------- post1: elementwise + kk-normalize (b staged NEGATED for scan) ----------
__global__ __launch_bounds__(256) void k_post1(
  u16* __restrict__ kb, u16* __restrict__ vb, const u16* __restrict__ winb,
  u16* __restrict__ ainb, u16* __restrict__ vinb,
  const float* __restrict__ vfirst,
  const float* __restrict__ w0, const float* __restrict__ a0, const float* __restrict__ v0,
  const float* __restrict__ kkv, const float* __restrict__ kav,
  float* __restrict__ dec)
{
  int grp = blockIdx.x*4 + (threadIdx.x >> 6);
  int n = threadIdx.x & 63;
  int i = grp >> 5, h = grp & 31;
  int c = h*64 + n;
  size_t idx = (size_t)i*CC + c;
  float k  = bf2f(kb[idx]),  v = bf2f(vb[idx]);
  float wi = bf2f(winb[idx]), ai = bf2f(ainb[idx]), vi = bf2f(vinb[idx]);
  float vf = vfirst[idx];
  float a  = 1.f/(1.f + expf(-(a0[c] + ai)));
  float z  = -(w0[c] + wi);
  float sp = (z > 15.f) ? z : log1pf(expf(z));
  float decay = expf(-expf(-sp - 0.5f));
  float vg = 1.f/(1.f + expf(-(v0[c] + vi)));
  float vfin = v + (vf - v)*vg;
  float kkr = k * kkv[c];
  float ss = wave_sum64(kkr*kkr);
  float kkn = kkr / fmaxf(sqrtf(ss), 1e-12f);
  float kfin = k * (1.f + (a - 1.f)*kav[c]);
  kb[idx] = f2bf(kfin);
  vb[idx] = f2bf(vfin);
  dec[idx] = decay;
  vinb[idx] = f2bf(kkn);
  ainb[idx] = f2bf(-(kkn * a));   // pre-negated b for the scan
}

// ---------- WKV scan v4: 1024 blocks = 8 row-octets x 128 (b,h); 64 threads (1 wave) ----------
// blk = oct*128 + bh  =>  XCD (blk%8) = bh%8: all 8 octets of a (b,h) share one XCD's L2,
// so the column vectors (w,b,k,kk,r) are fetched from HBM once per XCD, not 8x.
// Lane (rg=ln>>4, cg=ln&15): owns S[oct*8+rg*2 .. +1][cg*4 .. +3] in 8 registers.
// 4 rotating 4-step chunks: prefetch depth 3 (load->use distance 8-12 steps). No LDS.
#define DECL_CHUNK(S) float4 w##S[4]; ushort4 b##S[4], k##S[4], kk##S[4], r##S[4]; u32 v##S[4];

#define SCAN_ISSUE(S, t0) do {                                                   \
  _Pragma("unroll")                                                              \
  for (int s_=0; s_<4; ++s_){                                                    \
    size_t o_ = gc0 + (size_t)((t0)+s_)*CC;                                      \
    w##S[s_]  = *(const float4*)&wb[o_];                                         \
    b##S[s_]  = *(const ushort4*)&bbp[o_];                                       \
    k##S[s_]  = *(const ushort4*)&kb[o_];                                        \
    kk##S[s_] = *(const ushort4*)&kkb[o_];                                       \
    r##S[s_]  = *(const ushort4*)&rb[o_];                                        \
    v##S[s_]  = *(const u32*)&vb[gv0 + (size_t)((t0)+s_)*CC];                    \
  }                                                                              \
} while(0)

#define SCAN_CHUNK(S, t0) do {                                                   \
  _Pragma("unroll")                                                              \
  for (int s_=0; s_<4; ++s_){                                                    \
    const float w_0=w##S[s_].x, w_1=w##S[s_].y, w_2=w##S[s_].z, w_3=w##S[s_].w;  \
    const float b_0=bf2f(b##S[s_].x), b_1=bf2f(b##S[s_].y),                      \
                b_2=bf2f(b##S[s_].z), b_3=bf2f(b##S[s_].w);                      \
    const float k_0=bf2f(k##S[s_].x), k_1=bf2f(k##S[s_].y),                      \
                k_2=bf2f(k##S[s_].z), k_3=bf2f(k##S[s_].w);                      \
    const float q_0=bf2f(kk##S[s_].x), q_1=bf2f(kk##S[s_].y),                    \
                q_2=bf2f(kk##S[s_].z), q_3=bf2f(kk##S[s_].w);                    \
    const float r_0=bf2f(r##S[s_].x), r_1=bf2f(r##S[s_].y),                      \
                r_2=bf2f(r##S[s_].z), r_3=bf2f(r##S[s_].w);                      \
    const u32 vpk_ = v##S[s_];                                                   \
    const float vv0_ = bf2f((u16)(vpk_ & 0xFFFFu));                              \
    const float vv1_ = bf2f((u16)(vpk_ >> 16));                                  \
    float p0_ = fmaf(st[0][0],q_0, st[0][1]*q_1) + fmaf(st[0][2],q_2, st[0][3]*q_3); \
    float p1_ = fmaf(st[1][0],q_0, st[1][1]*q_1) + fmaf(st[1][2],q_2, st[1][3]*q_3); \
    p0_ = red16(p0_); p1_ = red16(p1_);                                          \
    st[0][0] = fmaf(st[0][0],w_0, fmaf(p0_,b_0, vv0_*k_0));                      \
    st[0][1] = fmaf(st[0][1],w_1, fmaf(p0_,b_1, vv0_*k_1));                      \
    st[0][2] = fmaf(st[0][2],w_2, fmaf(p0_,b_2, vv0_*k_2));                      \
    st[0][3] = fmaf(st[0][3],w_3, fmaf(p0_,b_3, vv0_*k_3));                      \
    st[1][0] = fmaf(st[1][0],w_0, fmaf(p1_,b_0, vv1_*k_0));                      \
    st[1][1] = fmaf(st[1][1],w_1, fmaf(p1_,b_1, vv1_*k_1));                      \
    st[1][2] = fmaf(st[1][2],w_2, fmaf(p1_,b_2, vv1_*k_2));                      \
    st[1][3] = fmaf(st[1][3],w_3, fmaf(p1_,b_3, vv1_*k_3));                      \
    float y0_ = fmaf(st[0][0],r_0, st[0][1]*r_1) + fmaf(st[0][2],r_2, st[0][3]*r_3); \
    float y1_ = fmaf(st[1][0],r_0, st[1][1]*r_1) + fmaf(st[1][2],r_2, st[1][3]*r_3); \
    y0_ = red16(y0_); y1_ = red16(y1_);                                          \
    if (cg == 0){                                                                \
      u32 pk_ = (u32)f2bf(y0_) | ((u32)f2bf(y1_) << 16);                         \
      *(u32*)&yb[gv0 + (size_t)((t0)+s_)*CC] = pk_;                              \
    }                                                                            \
  }                                                                              \
} while(0)

__global__ __launch_bounds__(64) void k_scan(
  const u16* __restrict__ rb, const float* __restrict__ wb,
  const u16* __restrict__ kb, const u16* __restrict__ vb,
  const u16* __restrict__ kkb, const u16* __restrict__ bbp,
  const float* __restrict__ wkv_in, u16* __restrict__ yb, float* __restrict__ wkv_out)
{
  const int blk = blockIdx.x;
  const int bh = blk & 127, oct = blk >> 7;   // XCD = blk%8 = bh%8: octets of bh share L2
  const int b = bh >> 5, h = bh & 31;
  const int ln = threadIdx.x;
  const int rg = ln >> 4;            // row pair group 0..3
  const int cg = ln & 15;            // col group 0..15
  const int row0 = oct*8 + rg*2;
  const int col0 = cg*4;

  float st[2][4];
  {
    const float* sp0 = &wkv_in[((size_t)bh*64 + row0    )*64 + col0];
    const float* sp1 = &wkv_in[((size_t)bh*64 + row0 + 1)*64 + col0];
    float4 a = *(const float4*)sp0, c = *(const float4*)sp1;
    st[0][0]=a.x; st[0][1]=a.y; st[0][2]=a.z; st[0][3]=a.w;
    st[1][0]=c.x; st[1][1]=c.y; st[1][2]=c.z; st[1][3]=c.w;
  }

  const size_t gc0 = ((size_t)b*TT)*CC + h*64 + col0;          // col-data base
  const size_t gv0 = ((size_t)b*TT)*CC + h*64 + row0;          // v / y base

  DECL_CHUNK(A) DECL_CHUNK(B) DECL_CHUNK(C) DECL_CHUNK(D)

  SCAN_ISSUE(A, 0);
  SCAN_ISSUE(B, 4);
  SCAN_ISSUE(C, 8);
  // 256 chunks of 4 steps, unrolled by 4 => 64 iterations exactly
  for (int it = 0; it < 64; ++it){
    const int t0 = it*16;
    if (t0+12 < TT) SCAN_ISSUE(D, t0+12);
    SCAN_CHUNK(A, t0);
    if (t0+16 < TT) SCAN_ISSUE(A, t0+16);
    SCAN_CHUNK(B, t0+4);
    if (t0+20 < TT) SCAN_ISSUE(B, t0+20);
    SCAN_CHUNK(C, t0+8);
    if (t0+24 < TT) SCAN_ISSUE(C, t0+24);
    SCAN_CHUNK(D, t0+12);
  }

  {
    float* wo0 = &wkv_out[((size_t)bh*64 + row0    )*64 + col0];
    float* wo1 = &wkv_out[((size_t)bh*64 + row0 + 1)*64 + col0];
    *(float4*)wo0 = make_float4(st[0][0], st[0][1], st[0][2], st[0][3]);
    *(float4*)wo1 = make_float4(st[1][0], st[1][1], st[1][2], st[1][3]);
  }
}

// ---------- post2 ----------
__global__ __launch_bounds__(256) void k_post2(
  const u16* __restrict__ ybuf, const u16* __restrict__ rbuf,
  const u16* __restrict__ kfb, const u16* __restrict__ vfb,
  const u16* __restrict__ gbuf, const float* __restrict__ rk,
  const float* __restrict__ lnw, const float* __restrict__ lnb, u16* __restrict__ ao)
{
  int grp = blockIdx.x*4 + (threadIdx.x >> 6);
  int n = threadIdx.x & 63;
  int i = grp >> 5, h = grp & 31;
  int c = h*64 + n;
  size_t idx = (size_t)i*CC + c;
  float y = bf2f(ybuf[idx]);
  float s1 = wave_sum64(y);
  float s2 = wave_sum64(y*y);
  float mu = s1 * (1.f/64.f);
  float var = s2 * (1.f/64.f) - mu*mu;
  float yn = (y - mu) * rsqrtf(var + 6.4e-4f) * lnw[c] + lnb[c];
  float rv = bf2f(rbuf[idx]), kv = bf2f(kfb[idx]);
  float s3 = wave_sum64(rv * kv * rk[c]);
  float bonus = s3 * bf2f(vfb[idx]);
  ao[idx] = f2bf((yn + bonus) * bf2f(gbuf[idx]));
}

// ---------- shift_state_out = x[:, -1] ----------
__global__ __launch_bounds__(256) void k_shift(const float* __restrict__ x, float* __restrict__ so){
  int i = blockIdx.x*256 + threadIdx.x;
  int b = i >> 9, c4 = (i & 511)*4;
  *(float4*)&so[(size_t)b*CC + c4] = *(const float4*)&x[((size_t)(b*TT + TT-1))*CC + c4];
}

// ---------- launch ----------
extern "C" void kernel_launch(void* const* d_in, const int* in_sizes, int n_in,
                              void* d_out, int out_size, void* d_ws, size_t ws_size,
                              hipStream_t stream)
{
  const float* x        = (const float*)d_in[0];
  const float* shift_in = (const float*)d_in[1];
  const float* wkv_in   = (const float*)d_in[2];
  const float* v_first  = (const float*)d_in[3];
  const float* x_r = (const float*)d_in[4];
  const float* x_w = (const float*)d_in[5];
  const float* x_k = (const float*)d_in[6];
  const float* x_v = (const float*)d_in[7];
  const float* x_a = (const float*)d_in[8];
  const float* x_g = (const float*)d_in[9];
  const float* w0 = (const float*)d_in[10];
  const float* w1 = (const float*)d_in[11];
  const float* w2 = (const float*)d_in[12];
  const float* a0 = (const float*)d_in[13];
  const float* a1 = (const float*)d_in[14];
  const float* a2 = (const float*)d_in[15];
  const float* v0 = (const float*)d_in[16];
  const float* v1 = (const float*)d_in[17];
  const float* v2 = (const float*)d_in[18];
  const float* g1 = (const float*)d_in[19];
  const float* g2 = (const float*)d_in[20];
  const float* k_k = (const float*)d_in[21];
  const float* k_a = (const float*)d_in[22];
  const float* r_k = (const float*)d_in[23];
  const float* Wr = (const float*)d_in[24];
  const float* Wk = (const float*)d_in[25];
  const float* Wv = (const float*)d_in[26];
  const float* Wo = (const float*)d_in[27];
  const float* ln_w = (const float*)d_in[28];
  const float* ln_b = (const float*)d_in[29];

  // ---- ws layout ----
  char* ws = (char*)d_ws;
  u16* WOB  = (u16*)(ws + 0);
  u16* WRB  = (u16*)(ws + 8388608);
  u16* WKB  = (u16*)(ws + 16777216);
  u16* WVB  = (u16*)(ws + 25165824);
  u16* WCAT = (u16*)(ws + 33554432);
  u16* B2W  = (u16*)(ws + 36175872);
  u16* B2A  = (u16*)(ws + 36700160);
  u16* B2V  = (u16*)(ws + 37224448);
  u16* B2G  = (u16*)(ws + 37748736);
  u16* PBUF = (u16*)(ws + 38797312);
  u16* RB   = (u16*)(ws + 44040192);
  u16* KB   = (u16*)(ws + 60817408);
  u16* VB   = (u16*)(ws + 77594624);
  u16* YB   = (u16*)(ws + 94371840);
  float* DEC  = (float*)(ws + 8388608);     // overlays dead WRB..PBUF (post1 -> scan)
  u16* AO   = (u16*)(ws + 8388608);         // overlays dead DEC (post2 -> final GEMM)

  // ---- d_out scratch ----
  float* out       = (float*)d_out;
  float* shift_out = out + 8388608;
  float* wkv_out   = out + 8396800;
  float* vf_out    = out + 8921088;
  u16* WINb = (u16*)d_out;
  u16* AINb = (u16*)((char*)d_out + 16777216);
  u16* VINb = (u16*)((char*)d_out + 35684352);
  u16* GB   = (u16*)((char*)d_out + 52461568);

  // weight casts
  k_cast<<<4096, 256, 0, stream>>>(Wr, WRB, 4194304);
  k_cast<<<4096, 256, 0, stream>>>(Wk, WKB, 4194304);
  k_cast<<<4096, 256, 0, stream>>>(Wv, WVB, 4194304);
  k_cast<<<4096, 256, 0, stream>>>(Wo, WOB, 4194304);

  // stage-1 fused weight + stage-2 weights
  k_tpad<<<1024, 256, 0, stream>>>(w1, WCAT,            2048,  96, 2048, 128);
  k_tpad<<<1024, 256, 0, stream>>>(a1, WCAT + 128*2048, 2048,  96, 2048, 128);
  k_tpad<<<1024, 256, 0, stream>>>(v1, WCAT + 256*2048, 2048,  64, 2048, 128);
  k_tpad<<<2048, 256, 0, stream>>>(g1, WCAT + 384*2048, 2048, 256, 2048, 256);
  k_tpad<<<1024, 256, 0, stream>>>(w2, B2W,  96, 2048, 128, 2048);
  k_tpad<<<1024, 256, 0, stream>>>(a2, B2A,  96, 2048, 128, 2048);
  k_tpad<<<1024, 256, 0, stream>>>(v2, B2V,  64, 2048, 128, 2048);
  k_tpad<<<2048, 256, 0, stream>>>(g2, B2G, 256, 2048, 256, 2048);

  // big GEMMs with fused token-shift mixing
  k_gemm<1,1><<<dim3(16,32), 256, 0, stream>>>(nullptr, x, shift_in, x_r, x_r, x_r, x_r,
                                               WRB, nullptr, RB, 2048, 0, 2048, 2048);
  k_gemm<1,1><<<dim3(16,32), 256, 0, stream>>>(nullptr, x, shift_in, x_k, x_k, x_k, x_k,
                                               WKB, nullptr, KB, 2048, 0, 2048, 2048);
  k_gemm<1,1><<<dim3(16,32), 256, 0, stream>>>(nullptr, x, shift_in, x_v, x_v, x_v, x_v,
                                               WVB, nullptr, VB, 2048, 0, 2048, 2048);

  // fused stage-1
  k_gemm<1,2><<<dim3(5,32), 256, 0, stream>>>(nullptr, x, shift_in, x_w, x_a, x_v, x_g,
                                              WCAT, nullptr, PBUF, 2048, 0, 2048, 640);

  // stage-2 GEMMs
  k_gemm<0,1><<<dim3(16,32), 256, 0, stream>>>(PBUF+0,   nullptr,nullptr,nullptr,nullptr,nullptr,nullptr,
                                               B2W, nullptr, WINb, 128, 640, 128, 2048);
  k_gemm<0,1><<<dim3(16,32), 256, 0, stream>>>(PBUF+128, nullptr,nullptr,nullptr,nullptr,nullptr,nullptr,
                                               B2A, nullptr, AINb, 128, 640, 128, 2048);
  k_gemm<0,1><<<dim3(16,32), 256, 0, stream>>>(PBUF+256, nullptr,nullptr,nullptr,nullptr,nullptr,nullptr,
                                               B2V, nullptr, VINb, 128, 640, 128, 2048);
  k_gemm<0,1><<<dim3(16,32), 256, 0, stream>>>(PBUF+384, nullptr,nullptr,nullptr,nullptr,nullptr,nullptr,
                                               B2G, nullptr, GB,   256, 640, 256, 2048);

  // elementwise post
  k_post1<<<32768, 256, 0, stream>>>(KB, VB, WINb, AINb, VINb, v_first,
                                     w0, a0, v0, k_k, k_a, DEC);

  // sequential WKV scan (register-resident, LDS-free, XCD-L2-shared)
  k_scan<<<1024, 64, 0, stream>>>(RB, DEC, KB, VB, VINb, AINb, wkv_in, YB, wkv_out);

  // groupnorm + bonus + gate
  k_post2<<<32768, 256, 0, stream>>>(YB, RB, KB, VB, GB, r_k, ln_w, ln_b, AO);

  // final GEMM -> out
  k_gemm<0,0><<<dim3(16,32), 256, 0, stream>>>(AO, nullptr,nullptr,nullptr,nullptr,nullptr,nullptr,
                                               WOB, out, nullptr, 2048, 2048, 2048, 2048);

  // small outputs last
  k_shift<<<8, 256, 0, stream>>>(x, shift_out);
  hipMemcpyAsync(vf_out, v_first, 33554432, hipMemcpyDeviceToDevice, stream);
}